// Round 5
// baseline (92.333 us; speedup 1.0000x reference)
//
#include <hip/hip_runtime.h>

#define BB 8
#define LL 32768
#define DD 64

typedef float f4 __attribute__((ext_vector_type(4)));

// ws layout:
// [0, 4096)              : double reduced_q[BB*DD] (zero-init via memsetAsync each call)
// [4096, 4096 + BB*LL*8) : double scores[BB*LL]    (2 MiB)

#define OUT_F4 (BB * LL * DD / 4)  // 4,194,304 float4s in out
#define ZPB 2048                   // float4 zeros per block (1024 blocks x half each)

// ---------------- Kernel 1: reduced_q[b,d] = sum_l relu(q[b,l,d]) + eps ----------------
// Also zero-fills the FIRST half of out (nontemporal).
__global__ __launch_bounds__(256) void k_reduce_q(const float* __restrict__ q,
                                                  double* __restrict__ rq,
                                                  float* __restrict__ out) {
    {
        f4 z = (f4)(0.0f);
        f4* oz = (f4*)out + (size_t)blockIdx.x * ZPB + threadIdx.x;
#pragma unroll
        for (int i = 0; i < ZPB / 256; ++i)
            __builtin_nontemporal_store(z, oz + i * 256);
    }

    const int CHUNKS = 128;          // blocks per batch
    const int ROWS   = LL / CHUNKS;  // 256 rows per block
    int b     = blockIdx.x / CHUNKS;
    int chunk = blockIdx.x % CHUNKS;
    int quad  = threadIdx.x & 15;
    int row   = threadIdx.x >> 4;

    const f4* qb = (const f4*)(q + (size_t)b * LL * DD);
    int l0 = chunk * ROWS;
    const f4* base = qb + (size_t)(l0 + row) * 16 + quad;

    double a0 = 0.0, a1 = 0.0, a2 = 0.0, a3 = 0.0;
    f4 vb[8];
#pragma unroll
    for (int batch = 0; batch < 2; ++batch) {
#pragma unroll
        for (int i = 0; i < 8; ++i)
            vb[i] = __builtin_nontemporal_load(base + (size_t)(batch * 8 + i) * 256);
#pragma unroll
        for (int i = 0; i < 8; ++i) {
            a0 += (double)fmaxf(vb[i].x, 0.0f) + 1e-3;
            a1 += (double)fmaxf(vb[i].y, 0.0f) + 1e-3;
            a2 += (double)fmaxf(vb[i].z, 0.0f) + 1e-3;
            a3 += (double)fmaxf(vb[i].w, 0.0f) + 1e-3;
        }
    }

    __shared__ double lds[16][16][4];
    lds[row][quad][0] = a0; lds[row][quad][1] = a1;
    lds[row][quad][2] = a2; lds[row][quad][3] = a3;
    __syncthreads();
    for (int s = 8; s > 0; s >>= 1) {
        if (row < s) {
            lds[row][quad][0] += lds[row + s][quad][0];
            lds[row][quad][1] += lds[row + s][quad][1];
            lds[row][quad][2] += lds[row + s][quad][2];
            lds[row][quad][3] += lds[row + s][quad][3];
        }
        __syncthreads();
    }
    if (row == 0) {
        atomicAdd(&rq[b * DD + quad * 4 + 0], lds[0][quad][0]);
        atomicAdd(&rq[b * DD + quad * 4 + 1], lds[0][quad][1]);
        atomicAdd(&rq[b * DD + quad * 4 + 2], lds[0][quad][2]);
        atomicAdd(&rq[b * DD + quad * 4 + 3], lds[0][quad][3]);
    }
}

// ---------------- Kernel 2: scores[b,l] = rq[b,:] . (relu(k[b,l,:]) + eps) ----------------
// Also zero-fills the SECOND half of out (nontemporal).
__global__ __launch_bounds__(256) void k_scores(const float* __restrict__ k,
                                                const double* __restrict__ rq,
                                                double* __restrict__ scores,
                                                float* __restrict__ out) {
    {
        f4 z = (f4)(0.0f);
        f4* oz = (f4*)out + (size_t)(OUT_F4 / 2)
               + (size_t)blockIdx.x * ZPB + threadIdx.x;
#pragma unroll
        for (int i = 0; i < ZPB / 256; ++i)
            __builtin_nontemporal_store(z, oz + i * 256);
    }

    const int RPB = 256;  // rows per block
    int b     = blockIdx.x / (LL / RPB);
    int chunk = blockIdx.x % (LL / RPB);
    int sub   = threadIdx.x & 15;
    int rowIn = threadIdx.x >> 4;

    double r0 = rq[b * DD + sub * 4 + 0];
    double r1 = rq[b * DD + sub * 4 + 1];
    double r2 = rq[b * DD + sub * 4 + 2];
    double r3 = rq[b * DD + sub * 4 + 3];

    const f4* kb = (const f4*)(k + (size_t)b * LL * DD);
    int l0 = chunk * RPB;
    const f4* base = kb + (size_t)(l0 + rowIn) * 16 + sub;

    f4 vb[8];
    double sv[8];
#pragma unroll
    for (int batch = 0; batch < 2; ++batch) {
#pragma unroll
        for (int i = 0; i < 8; ++i)
            vb[i] = __builtin_nontemporal_load(base + (size_t)(batch * 8 + i) * 256);
#pragma unroll
        for (int i = 0; i < 8; ++i) {
            sv[i] = r0 * ((double)fmaxf(vb[i].x, 0.0f) + 1e-3)
                  + r1 * ((double)fmaxf(vb[i].y, 0.0f) + 1e-3)
                  + r2 * ((double)fmaxf(vb[i].z, 0.0f) + 1e-3)
                  + r3 * ((double)fmaxf(vb[i].w, 0.0f) + 1e-3);
        }
#pragma unroll
        for (int i = 0; i < 8; ++i) {
            double s = sv[i];
            s += __shfl_xor(s, 1, 16);
            s += __shfl_xor(s, 2, 16);
            s += __shfl_xor(s, 4, 16);
            s += __shfl_xor(s, 8, 16);
            if (sub == 0)
                scores[(size_t)b * LL + l0 + rowIn + 16 * (batch * 8 + i)] = s;
        }
    }
}

// ---------------- Kernel 3: radix select + gather selected V rows ----------------
#define NCOPY 16
#define HSTRIDE 257
#define MAXSEL 96
__global__ __launch_bounds__(1024) void k_select_gather(const double* __restrict__ scores,
                                                        const int* __restrict__ topk_p,
                                                        const float* __restrict__ v,
                                                        float* __restrict__ out) {
    const int T = 1024;
    const int KPT = LL / T;  // 32
    int b   = blockIdx.x;
    int tid = threadIdx.x;

    const unsigned long long* sb =
        (const unsigned long long*)(scores + (size_t)b * LL);

    unsigned long long key[KPT];
    unsigned long long myAnd = ~0ULL, myOr = 0ULL;
#pragma unroll
    for (int i = 0; i < KPT; ++i) {
        key[i] = sb[tid + i * T];
        myAnd &= key[i];
        myOr  |= key[i];
    }

    __shared__ unsigned long long sAnd[16], sOr[16];
#pragma unroll
    for (int off = 32; off >= 1; off >>= 1) {
        myAnd &= __shfl_down(myAnd, off);
        myOr  |= __shfl_down(myOr, off);
    }
    int wave = tid >> 6;
    if ((tid & 63) == 0) { sAnd[wave] = myAnd; sOr[wave] = myOr; }
    __syncthreads();
    __shared__ unsigned long long bAnd, bOr;
    if (tid == 0) {
        unsigned long long a = ~0ULL, o = 0ULL;
#pragma unroll
        for (int w = 0; w < 16; ++w) { a &= sAnd[w]; o |= sOr[w]; }
        bAnd = a; bOr = o;
    }

    __shared__ unsigned int hist[NCOPY * HSTRIDE];
    __shared__ unsigned int sTot[256];
    __shared__ unsigned long long sh_prefix;
    __shared__ int sh_r;
    __shared__ int sh_digit, sh_newr;
    if (tid == 0) { sh_prefix = 0ULL; sh_r = topk_p[0]; }
    __syncthreads();

    int copy = tid & (NCOPY - 1);

    for (int shift = 56; shift >= 0; shift -= 8) {
        unsigned int dA = (unsigned int)(bAnd >> shift) & 255u;
        unsigned int dO = (unsigned int)(bOr  >> shift) & 255u;
        if (dA == dO) {
            if (tid == 0) sh_prefix |= ((unsigned long long)dA << shift);
            __syncthreads();
            continue;
        }

        for (int i = tid; i < NCOPY * HSTRIDE; i += T) hist[i] = 0;
        __syncthreads();

        unsigned long long prefix = sh_prefix;
        unsigned long long hm = (shift == 56) ? 0ULL : (~0ULL << (shift + 8));
        int r = sh_r;

#pragma unroll
        for (int i = 0; i < KPT; ++i) {
            unsigned long long kk = key[i];
            if ((kk & hm) == prefix) {
                unsigned int d = (unsigned int)(kk >> shift) & 255u;
                atomicAdd(&hist[copy * HSTRIDE + d], 1u);
            }
        }
        __syncthreads();

        if (tid < 256) {
            unsigned int t = 0;
#pragma unroll
            for (int c = 0; c < NCOPY; ++c) t += hist[c * HSTRIDE + tid];
            sTot[tid] = t;
        }
        __syncthreads();

        for (int s = 1; s < 256; s <<= 1) {
            unsigned int vv = 0;
            if (tid < 256 && tid + s < 256) vv = sTot[tid + s];
            __syncthreads();
            if (tid < 256) sTot[tid] += vv;
            __syncthreads();
        }

        if (tid < 256) {
            unsigned int suf  = sTot[tid];
            unsigned int sufn = (tid == 255) ? 0u : sTot[tid + 1];
            if (suf > (unsigned int)r && sufn <= (unsigned int)r) {
                sh_digit = tid;
                sh_newr  = r - (int)sufn;
            }
        }
        __syncthreads();
        if (tid == 0) {
            sh_prefix |= ((unsigned long long)sh_digit << shift);
            sh_r = sh_newr;
        }
        __syncthreads();
    }

    // ---- gather phase: rows with key > cutoff get V copied into out ----
    __shared__ int s_cnt;
    __shared__ int s_idx[MAXSEL];
    if (tid == 0) s_cnt = 0;
    __syncthreads();
    unsigned long long cb = sh_prefix;
#pragma unroll
    for (int i = 0; i < KPT; ++i) {
        if (key[i] > cb) {
            int slot = atomicAdd(&s_cnt, 1);
            if (slot < MAXSEL) s_idx[slot] = tid + i * T;
        }
    }
    __syncthreads();
    int cnt = s_cnt < MAXSEL ? s_cnt : MAXSEL;

    int g      = tid >> 4;   // 64 groups of 16 lanes
    int lane16 = tid & 15;
    for (int r = g; r < cnt; r += 64) {
        size_t rowOff = ((size_t)b * LL + s_idx[r]) * DD;
        const f4* vrow = (const f4*)(v + rowOff);
        f4*       orow = (f4*)(out + rowOff);
        orow[lane16] = vrow[lane16];
    }
}

extern "C" void kernel_launch(void* const* d_in, const int* in_sizes, int n_in,
                              void* d_out, int out_size, void* d_ws, size_t ws_size,
                              hipStream_t stream) {
    const float* q = (const float*)d_in[0];
    const float* k = (const float*)d_in[1];
    const float* v = (const float*)d_in[2];
    const int* topk = (const int*)d_in[3];
    float* out = (float*)d_out;

    double* rq     = (double*)d_ws;
    double* scores = (double*)((char*)d_ws + 4096);

    (void)hipMemsetAsync(d_ws, 0, BB * DD * sizeof(double), stream);

    k_reduce_q<<<BB * 128, 256, 0, stream>>>(q, rq, out);
    k_scores<<<BB * (LL / 256), 256, 0, stream>>>(k, rq, scores, out);
    k_select_gather<<<BB, 1024, 0, stream>>>(scores, topk, v, out);
}

// Round 6
// 74.897 us; speedup vs baseline: 1.2328x; 1.2328x over previous
//
#include <hip/hip_runtime.h>

#define BB 8
#define LL 32768
#define DD 64

typedef float f4 __attribute__((ext_vector_type(4)));

// ws layout:
// [0, 32768)               : double rq_pad[512*8]  -- rq[b*64+d] lives at index (b*64+d)*8
//                            (one double per 64B cache line; zeroed via memsetAsync)
// [32768, 32768 + BB*LL*8) : double scores[BB*LL]  (2 MiB)

#define OUT_F4 (BB * LL * DD / 4)  // 4,194,304 float4s in out
#define CHUNKS_Q 32                // blocks per batch in k_reduce_q
#define ROWS_Q (LL / CHUNKS_Q)     // 1024 rows per block

// ---------------- Kernel 1: reduced_q[b,d] = sum_l relu(q[b,l,d]) + eps ----------------
// 256 blocks x 256 threads. Also zero-fills the FIRST half of out.
__global__ __launch_bounds__(256) void k_reduce_q(const float* __restrict__ q,
                                                  double* __restrict__ rq,
                                                  float* __restrict__ out) {
    // zero-fill: 2,097,152 f4 / 256 blocks = 8192 per block = 32 per thread
    {
        f4 z = (f4)(0.0f);
        f4* oz = (f4*)out + (size_t)blockIdx.x * 8192 + threadIdx.x;
#pragma unroll
        for (int i = 0; i < 32; ++i) oz[i * 256] = z;
    }

    int b     = blockIdx.x >> 5;         // /CHUNKS_Q
    int chunk = blockIdx.x & (CHUNKS_Q - 1);
    int quad  = threadIdx.x & 15;        // which float4 of the 64-wide row
    int rowg  = threadIdx.x >> 4;        // 16 row-groups

    const f4* qb = (const f4*)(q + (size_t)b * LL * DD);
    const f4* base = qb + (size_t)(chunk * ROWS_Q + rowg) * 16 + quad;

    double a0 = 0.0, a1 = 0.0, a2 = 0.0, a3 = 0.0;
    f4 vb[8];
#pragma unroll
    for (int batch = 0; batch < 8; ++batch) {
#pragma unroll
        for (int j = 0; j < 8; ++j)
            vb[j] = base[(size_t)(batch * 8 + j) * 256];   // stride: 16 rows = 256 f4
#pragma unroll
        for (int j = 0; j < 8; ++j) {
            a0 += (double)fmaxf(vb[j].x, 0.0f) + 1e-3;
            a1 += (double)fmaxf(vb[j].y, 0.0f) + 1e-3;
            a2 += (double)fmaxf(vb[j].z, 0.0f) + 1e-3;
            a3 += (double)fmaxf(vb[j].w, 0.0f) + 1e-3;
        }
    }

    __shared__ double lds[16][16][5];   // [5] pads away bank conflicts
    lds[rowg][quad][0] = a0; lds[rowg][quad][1] = a1;
    lds[rowg][quad][2] = a2; lds[rowg][quad][3] = a3;
    __syncthreads();
    for (int s = 8; s > 0; s >>= 1) {
        if (rowg < s) {
            lds[rowg][quad][0] += lds[rowg + s][quad][0];
            lds[rowg][quad][1] += lds[rowg + s][quad][1];
            lds[rowg][quad][2] += lds[rowg + s][quad][2];
            lds[rowg][quad][3] += lds[rowg + s][quad][3];
        }
        __syncthreads();
    }
    if (rowg == 0) {
        // padded: one accumulator per 64B line -> only 32-way contention per line
        atomicAdd(&rq[(size_t)(b * DD + quad * 4 + 0) * 8], lds[0][quad][0]);
        atomicAdd(&rq[(size_t)(b * DD + quad * 4 + 1) * 8], lds[0][quad][1]);
        atomicAdd(&rq[(size_t)(b * DD + quad * 4 + 2) * 8], lds[0][quad][2]);
        atomicAdd(&rq[(size_t)(b * DD + quad * 4 + 3) * 8], lds[0][quad][3]);
    }
}

// ---------------- Kernel 2: scores[b,l] = rq[b,:] . (relu(k[b,l,:]) + eps) ----------------
// 1024 blocks x 256 threads, 256 rows each. Also zero-fills the SECOND half of out.
__global__ __launch_bounds__(256) void k_scores(const float* __restrict__ k,
                                                const double* __restrict__ rq,
                                                double* __restrict__ scores,
                                                float* __restrict__ out) {
    {
        f4 z = (f4)(0.0f);
        f4* oz = (f4*)out + (size_t)(OUT_F4 / 2)
               + (size_t)blockIdx.x * 2048 + threadIdx.x;
#pragma unroll
        for (int i = 0; i < 8; ++i) oz[i * 256] = z;
    }

    const int RPB = 256;
    int b     = blockIdx.x >> 7;          // /(LL/RPB)
    int chunk = blockIdx.x & 127;
    int sub   = threadIdx.x & 15;
    int rowIn = threadIdx.x >> 4;

    double r0 = rq[(size_t)(b * DD + sub * 4 + 0) * 8];
    double r1 = rq[(size_t)(b * DD + sub * 4 + 1) * 8];
    double r2 = rq[(size_t)(b * DD + sub * 4 + 2) * 8];
    double r3 = rq[(size_t)(b * DD + sub * 4 + 3) * 8];

    const f4* kb = (const f4*)(k + (size_t)b * LL * DD);
    int l0 = chunk * RPB;
    const f4* base = kb + (size_t)(l0 + rowIn) * 16 + sub;

    f4 vb[8];
    double sv[8];
#pragma unroll
    for (int batch = 0; batch < 2; ++batch) {
#pragma unroll
        for (int i = 0; i < 8; ++i)
            vb[i] = base[(size_t)(batch * 8 + i) * 256];
#pragma unroll
        for (int i = 0; i < 8; ++i) {
            sv[i] = r0 * ((double)fmaxf(vb[i].x, 0.0f) + 1e-3)
                  + r1 * ((double)fmaxf(vb[i].y, 0.0f) + 1e-3)
                  + r2 * ((double)fmaxf(vb[i].z, 0.0f) + 1e-3)
                  + r3 * ((double)fmaxf(vb[i].w, 0.0f) + 1e-3);
        }
#pragma unroll
        for (int i = 0; i < 8; ++i) {
            double s = sv[i];
            s += __shfl_xor(s, 1, 16);
            s += __shfl_xor(s, 2, 16);
            s += __shfl_xor(s, 4, 16);
            s += __shfl_xor(s, 8, 16);
            if (sub == 0)
                scores[(size_t)b * LL + l0 + rowIn + 16 * (batch * 8 + i)] = s;
        }
    }
}

// ---------------- Kernel 3: radix select + gather selected V rows ----------------
#define NCOPY 16
#define HSTRIDE 257
#define MAXSEL 96
__global__ __launch_bounds__(1024) void k_select_gather(const double* __restrict__ scores,
                                                        const int* __restrict__ topk_p,
                                                        const float* __restrict__ v,
                                                        float* __restrict__ out) {
    const int T = 1024;
    const int KPT = LL / T;  // 32
    int b   = blockIdx.x;
    int tid = threadIdx.x;

    const unsigned long long* sb =
        (const unsigned long long*)(scores + (size_t)b * LL);

    unsigned long long key[KPT];
    unsigned long long myAnd = ~0ULL, myOr = 0ULL;
#pragma unroll
    for (int i = 0; i < KPT; ++i) {
        key[i] = sb[tid + i * T];
        myAnd &= key[i];
        myOr  |= key[i];
    }

    __shared__ unsigned long long sAnd[16], sOr[16];
#pragma unroll
    for (int off = 32; off >= 1; off >>= 1) {
        myAnd &= __shfl_down(myAnd, off);
        myOr  |= __shfl_down(myOr, off);
    }
    int wave = tid >> 6;
    if ((tid & 63) == 0) { sAnd[wave] = myAnd; sOr[wave] = myOr; }
    __syncthreads();
    __shared__ unsigned long long bAnd, bOr;
    if (tid == 0) {
        unsigned long long a = ~0ULL, o = 0ULL;
#pragma unroll
        for (int w = 0; w < 16; ++w) { a &= sAnd[w]; o |= sOr[w]; }
        bAnd = a; bOr = o;
    }

    __shared__ unsigned int hist[NCOPY * HSTRIDE];
    __shared__ unsigned int sTot[256];
    __shared__ unsigned long long sh_prefix;
    __shared__ int sh_r;
    __shared__ int sh_digit, sh_newr;
    if (tid == 0) { sh_prefix = 0ULL; sh_r = topk_p[0]; }
    __syncthreads();

    int copy = tid & (NCOPY - 1);

    for (int shift = 56; shift >= 0; shift -= 8) {
        unsigned int dA = (unsigned int)(bAnd >> shift) & 255u;
        unsigned int dO = (unsigned int)(bOr  >> shift) & 255u;
        if (dA == dO) {
            if (tid == 0) sh_prefix |= ((unsigned long long)dA << shift);
            __syncthreads();
            continue;
        }

        for (int i = tid; i < NCOPY * HSTRIDE; i += T) hist[i] = 0;
        __syncthreads();

        unsigned long long prefix = sh_prefix;
        unsigned long long hm = (shift == 56) ? 0ULL : (~0ULL << (shift + 8));
        int r = sh_r;

#pragma unroll
        for (int i = 0; i < KPT; ++i) {
            unsigned long long kk = key[i];
            if ((kk & hm) == prefix) {
                unsigned int d = (unsigned int)(kk >> shift) & 255u;
                atomicAdd(&hist[copy * HSTRIDE + d], 1u);
            }
        }
        __syncthreads();

        if (tid < 256) {
            unsigned int t = 0;
#pragma unroll
            for (int c = 0; c < NCOPY; ++c) t += hist[c * HSTRIDE + tid];
            sTot[tid] = t;
        }
        __syncthreads();

        for (int s = 1; s < 256; s <<= 1) {
            unsigned int vv = 0;
            if (tid < 256 && tid + s < 256) vv = sTot[tid + s];
            __syncthreads();
            if (tid < 256) sTot[tid] += vv;
            __syncthreads();
        }

        if (tid < 256) {
            unsigned int suf  = sTot[tid];
            unsigned int sufn = (tid == 255) ? 0u : sTot[tid + 1];
            if (suf > (unsigned int)r && sufn <= (unsigned int)r) {
                sh_digit = tid;
                sh_newr  = r - (int)sufn;
            }
        }
        __syncthreads();
        if (tid == 0) {
            sh_prefix |= ((unsigned long long)sh_digit << shift);
            sh_r = sh_newr;
        }
        __syncthreads();
    }

    // ---- gather phase: rows with key > cutoff get V copied into out ----
    __shared__ int s_cnt;
    __shared__ int s_idx[MAXSEL];
    if (tid == 0) s_cnt = 0;
    __syncthreads();
    unsigned long long cb = sh_prefix;
#pragma unroll
    for (int i = 0; i < KPT; ++i) {
        if (key[i] > cb) {
            int slot = atomicAdd(&s_cnt, 1);
            if (slot < MAXSEL) s_idx[slot] = tid + i * T;
        }
    }
    __syncthreads();
    int cnt = s_cnt < MAXSEL ? s_cnt : MAXSEL;

    int g      = tid >> 4;   // 64 groups of 16 lanes
    int lane16 = tid & 15;
    for (int r = g; r < cnt; r += 64) {
        size_t rowOff = ((size_t)b * LL + s_idx[r]) * DD;
        const f4* vrow = (const f4*)(v + rowOff);
        f4*       orow = (f4*)(out + rowOff);
        orow[lane16] = vrow[lane16];
    }
}

extern "C" void kernel_launch(void* const* d_in, const int* in_sizes, int n_in,
                              void* d_out, int out_size, void* d_ws, size_t ws_size,
                              hipStream_t stream) {
    const float* q = (const float*)d_in[0];
    const float* k = (const float*)d_in[1];
    const float* v = (const float*)d_in[2];
    const int* topk = (const int*)d_in[3];
    float* out = (float*)d_out;

    double* rq     = (double*)d_ws;                      // padded, 32 KB
    double* scores = (double*)((char*)d_ws + 32768);

    (void)hipMemsetAsync(d_ws, 0, 32768, stream);

    k_reduce_q<<<BB * CHUNKS_Q, 256, 0, stream>>>(q, rq, out);
    k_scores<<<BB * (LL / 256), 256, 0, stream>>>(k, rq, scores, out);
    k_select_gather<<<BB, 1024, 0, stream>>>(scores, topk, v, out);
}

// Round 7
// 59.514 us; speedup vs baseline: 1.5515x; 1.2585x over previous
//
#include <hip/hip_runtime.h>

#define BB 8
#define LL 32768
#define DD 64

typedef float f4 __attribute__((ext_vector_type(4)));
typedef unsigned long long u64x2 __attribute__((ext_vector_type(2)));

// ws layout:
// [0, 32768)               : double rq_pad[512*8]  -- rq[b*64+d] at index (b*64+d)*8
//                            (one double per 64B cache line; zeroed via memsetAsync)
// [32768, 32768 + BB*LL*8) : double scores[BB*LL]  (2 MiB)

#define OUT_F4 (BB * LL * DD / 4)  // 4,194,304 float4s in out
#define CHUNKS_Q 64                // blocks per batch in k_reduce_q
#define ROWS_Q (LL / CHUNKS_Q)     // 512 rows per block

// ---------------- Kernel 1: reduced_q[b,d] = sum_l relu(q[b,l,d]) + eps ----------------
// 512 blocks x 256 threads. Also zero-fills the FIRST half of out.
__global__ __launch_bounds__(256) void k_reduce_q(const float* __restrict__ q,
                                                  double* __restrict__ rq,
                                                  float* __restrict__ out) {
    // zero-fill: 2,097,152 f4 / 512 blocks = 4096 per block = 16 per thread
    {
        f4 z = (f4)(0.0f);
        f4* oz = (f4*)out + (size_t)blockIdx.x * 4096 + threadIdx.x;
#pragma unroll
        for (int i = 0; i < 16; ++i) oz[i * 256] = z;
    }

    int b     = blockIdx.x >> 6;           // /CHUNKS_Q
    int chunk = blockIdx.x & (CHUNKS_Q - 1);
    int quad  = threadIdx.x & 15;          // which float4 of the 64-wide row
    int rowg  = threadIdx.x >> 4;          // 16 row-groups

    const f4* qb = (const f4*)(q + (size_t)b * LL * DD);
    const f4* base = qb + (size_t)(chunk * ROWS_Q + rowg) * 16 + quad;

    double a0 = 0.0, a1 = 0.0, a2 = 0.0, a3 = 0.0;
    f4 vb[8];
#pragma unroll
    for (int batch = 0; batch < 4; ++batch) {
#pragma unroll
        for (int j = 0; j < 8; ++j)
            vb[j] = base[(size_t)(batch * 8 + j) * 256];   // 16 rows = 256 f4 stride
#pragma unroll
        for (int j = 0; j < 8; ++j) {
            a0 += (double)fmaxf(vb[j].x, 0.0f) + 1e-3;
            a1 += (double)fmaxf(vb[j].y, 0.0f) + 1e-3;
            a2 += (double)fmaxf(vb[j].z, 0.0f) + 1e-3;
            a3 += (double)fmaxf(vb[j].w, 0.0f) + 1e-3;
        }
    }

    __shared__ double lds[16][16][5];   // [5] pads away bank conflicts
    lds[rowg][quad][0] = a0; lds[rowg][quad][1] = a1;
    lds[rowg][quad][2] = a2; lds[rowg][quad][3] = a3;
    __syncthreads();
    for (int s = 8; s > 0; s >>= 1) {
        if (rowg < s) {
            lds[rowg][quad][0] += lds[rowg + s][quad][0];
            lds[rowg][quad][1] += lds[rowg + s][quad][1];
            lds[rowg][quad][2] += lds[rowg + s][quad][2];
            lds[rowg][quad][3] += lds[rowg + s][quad][3];
        }
        __syncthreads();
    }
    if (rowg == 0) {
        atomicAdd(&rq[(size_t)(b * DD + quad * 4 + 0) * 8], lds[0][quad][0]);
        atomicAdd(&rq[(size_t)(b * DD + quad * 4 + 1) * 8], lds[0][quad][1]);
        atomicAdd(&rq[(size_t)(b * DD + quad * 4 + 2) * 8], lds[0][quad][2]);
        atomicAdd(&rq[(size_t)(b * DD + quad * 4 + 3) * 8], lds[0][quad][3]);
    }
}

// ---------------- Kernel 2: scores[b,l] = rq[b,:] . (relu(k[b,l,:]) + eps) ----------------
// 1024 blocks x 256 threads, 256 rows each. Also zero-fills the SECOND half of out.
__global__ __launch_bounds__(256) void k_scores(const float* __restrict__ k,
                                                const double* __restrict__ rq,
                                                double* __restrict__ scores,
                                                float* __restrict__ out) {
    {
        f4 z = (f4)(0.0f);
        f4* oz = (f4*)out + (size_t)(OUT_F4 / 2)
               + (size_t)blockIdx.x * 2048 + threadIdx.x;
#pragma unroll
        for (int i = 0; i < 8; ++i) oz[i * 256] = z;
    }

    const int RPB = 256;
    int b     = blockIdx.x >> 7;          // /(LL/RPB)
    int chunk = blockIdx.x & 127;
    int sub   = threadIdx.x & 15;
    int rowIn = threadIdx.x >> 4;

    double r0 = rq[(size_t)(b * DD + sub * 4 + 0) * 8];
    double r1 = rq[(size_t)(b * DD + sub * 4 + 1) * 8];
    double r2 = rq[(size_t)(b * DD + sub * 4 + 2) * 8];
    double r3 = rq[(size_t)(b * DD + sub * 4 + 3) * 8];

    const f4* kb = (const f4*)(k + (size_t)b * LL * DD);
    int l0 = chunk * RPB;
    const f4* base = kb + (size_t)(l0 + rowIn) * 16 + sub;

    f4 vb[8];
    double sv[8];
#pragma unroll
    for (int batch = 0; batch < 2; ++batch) {
#pragma unroll
        for (int i = 0; i < 8; ++i)
            vb[i] = base[(size_t)(batch * 8 + i) * 256];
#pragma unroll
        for (int i = 0; i < 8; ++i) {
            sv[i] = r0 * ((double)fmaxf(vb[i].x, 0.0f) + 1e-3)
                  + r1 * ((double)fmaxf(vb[i].y, 0.0f) + 1e-3)
                  + r2 * ((double)fmaxf(vb[i].z, 0.0f) + 1e-3)
                  + r3 * ((double)fmaxf(vb[i].w, 0.0f) + 1e-3);
        }
#pragma unroll
        for (int i = 0; i < 8; ++i) {
            double s = sv[i];
            s += __shfl_xor(s, 1, 16);
            s += __shfl_xor(s, 2, 16);
            s += __shfl_xor(s, 4, 16);
            s += __shfl_xor(s, 8, 16);
            if (sub == 0)
                scores[(size_t)b * LL + l0 + rowIn + 16 * (batch * 8 + i)] = s;
        }
    }
}

// ---------------- Kernel 3: radix select + gather selected V rows ----------------
// One block per batch, 1024 threads, 32 keys/thread (loaded as 16x 16B vectors).
// Positive doubles -> uint64 bit pattern preserves ordering.
// Early exit: once the chosen radix bucket holds exactly 1 key, that key IS the cutoff.
#define NCOPY 16
#define HSTRIDE 257
#define MAXSEL 96
__global__ __launch_bounds__(1024) void k_select_gather(const double* __restrict__ scores,
                                                        const int* __restrict__ topk_p,
                                                        const float* __restrict__ v,
                                                        float* __restrict__ out) {
    const int T = 1024;
    const int KPT = LL / T;  // 32
    int b   = blockIdx.x;
    int tid = threadIdx.x;

    const u64x2* sb2 = (const u64x2*)(scores + (size_t)b * LL);

    // key[2j] = element 2*(tid + j*T), key[2j+1] = +1
    unsigned long long key[KPT];
    unsigned long long myAnd = ~0ULL, myOr = 0ULL;
#pragma unroll
    for (int j = 0; j < KPT / 2; ++j) {
        u64x2 p = sb2[tid + j * T];
        key[2 * j]     = p.x;
        key[2 * j + 1] = p.y;
        myAnd &= p.x & p.y;
        myOr  |= p.x | p.y;
    }

    __shared__ unsigned long long sAnd[16], sOr[16];
#pragma unroll
    for (int off = 32; off >= 1; off >>= 1) {
        myAnd &= __shfl_down(myAnd, off);
        myOr  |= __shfl_down(myOr, off);
    }
    int wave = tid >> 6;
    if ((tid & 63) == 0) { sAnd[wave] = myAnd; sOr[wave] = myOr; }
    __syncthreads();
    __shared__ unsigned long long bAnd, bOr;
    if (tid == 0) {
        unsigned long long a = ~0ULL, o = 0ULL;
#pragma unroll
        for (int w = 0; w < 16; ++w) { a &= sAnd[w]; o |= sOr[w]; }
        bAnd = a; bOr = o;
    }

    __shared__ unsigned int hist[NCOPY * HSTRIDE];
    __shared__ unsigned int sTot[256];
    __shared__ unsigned long long sh_prefix;
    __shared__ int sh_r;
    __shared__ int sh_digit, sh_newr, sh_cnt, sh_done;
    if (tid == 0) { sh_prefix = 0ULL; sh_r = topk_p[0]; sh_done = 0; }
    __syncthreads();

    int copy = tid & (NCOPY - 1);

    for (int shift = 56; shift >= 0; shift -= 8) {
        if (sh_done) break;

        unsigned int dA = (unsigned int)(bAnd >> shift) & 255u;
        unsigned int dO = (unsigned int)(bOr  >> shift) & 255u;
        if (dA == dO) {
            if (tid == 0) sh_prefix |= ((unsigned long long)dA << shift);
            __syncthreads();
            continue;
        }

        for (int i = tid; i < NCOPY * HSTRIDE; i += T) hist[i] = 0;
        __syncthreads();

        unsigned long long prefix = sh_prefix;
        unsigned long long hm = (shift == 56) ? 0ULL : (~0ULL << (shift + 8));
        int r = sh_r;

#pragma unroll
        for (int i = 0; i < KPT; ++i) {
            unsigned long long kk = key[i];
            if ((kk & hm) == prefix) {
                unsigned int d = (unsigned int)(kk >> shift) & 255u;
                atomicAdd(&hist[copy * HSTRIDE + d], 1u);
            }
        }
        __syncthreads();

        if (tid < 256) {
            unsigned int t = 0;
#pragma unroll
            for (int c = 0; c < NCOPY; ++c) t += hist[c * HSTRIDE + tid];
            sTot[tid] = t;
        }
        __syncthreads();

        // reverse inclusive scan: sTot[i] = sum_{j>=i} tot[j]
        for (int s = 1; s < 256; s <<= 1) {
            unsigned int vv = 0;
            if (tid < 256 && tid + s < 256) vv = sTot[tid + s];
            __syncthreads();
            if (tid < 256) sTot[tid] += vv;
            __syncthreads();
        }

        if (tid < 256) {
            unsigned int suf  = sTot[tid];
            unsigned int sufn = (tid == 255) ? 0u : sTot[tid + 1];
            if (suf > (unsigned int)r && sufn <= (unsigned int)r) {
                sh_digit = tid;
                sh_newr  = r - (int)sufn;
                sh_cnt   = (int)(suf - sufn);
            }
        }
        __syncthreads();
        if (tid == 0) {
            sh_prefix |= ((unsigned long long)sh_digit << shift);
            sh_r = sh_newr;
        }
        __syncthreads();

        // Early exit: unique key in the chosen bucket -> it IS the cutoff.
        if (sh_cnt == 1 && shift > 0) {
            unsigned long long pfx = sh_prefix;
            unsigned long long hm2 = ~0ULL << shift;
#pragma unroll
            for (int i = 0; i < KPT; ++i) {
                if ((key[i] & hm2) == pfx) {
                    sh_prefix = key[i];   // unique owner
                    sh_done = 1;
                }
            }
        }
        __syncthreads();
    }

    // ---- gather phase: rows with key > cutoff get V copied into out ----
    __shared__ int s_cnt;
    __shared__ int s_idx[MAXSEL];
    if (tid == 0) s_cnt = 0;
    __syncthreads();
    unsigned long long cb = sh_prefix;
#pragma unroll
    for (int i = 0; i < KPT; ++i) {
        if (key[i] > cb) {
            int slot = atomicAdd(&s_cnt, 1);
            if (slot < MAXSEL)
                s_idx[slot] = 2 * (tid + (i >> 1) * T) + (i & 1);
        }
    }
    __syncthreads();
    int cnt = s_cnt < MAXSEL ? s_cnt : MAXSEL;

    int g      = tid >> 4;   // 64 groups of 16 lanes
    int lane16 = tid & 15;
    for (int r = g; r < cnt; r += 64) {
        size_t rowOff = ((size_t)b * LL + s_idx[r]) * DD;
        const f4* vrow = (const f4*)(v + rowOff);
        f4*       orow = (f4*)(out + rowOff);
        orow[lane16] = vrow[lane16];
    }
}

extern "C" void kernel_launch(void* const* d_in, const int* in_sizes, int n_in,
                              void* d_out, int out_size, void* d_ws, size_t ws_size,
                              hipStream_t stream) {
    const float* q = (const float*)d_in[0];
    const float* k = (const float*)d_in[1];
    const float* v = (const float*)d_in[2];
    const int* topk = (const int*)d_in[3];
    float* out = (float*)d_out;

    double* rq     = (double*)d_ws;                      // padded, 32 KB
    double* scores = (double*)((char*)d_ws + 32768);

    (void)hipMemsetAsync(d_ws, 0, 32768, stream);

    k_reduce_q<<<BB * CHUNKS_Q, 256, 0, stream>>>(q, rq, out);
    k_scores<<<BB * (LL / 256), 256, 0, stream>>>(k, rq, scores, out);
    k_select_gather<<<BB, 1024, 0, stream>>>(scores, topk, v, out);
}

// Round 8
// 56.255 us; speedup vs baseline: 1.6413x; 1.0579x over previous
//
#include <hip/hip_runtime.h>

#define BB 8
#define LL 32768
#define DD 64

typedef float f4 __attribute__((ext_vector_type(4)));
typedef unsigned long long u64x2 __attribute__((ext_vector_type(2)));

// ws layout:
// [0, 256K)            : double part[BB][CHUNKS_Q][DD] partial q-sums (fully written by k1)
// [256K, 256K+BB*LL*8) : double scores[BB*LL]  (2 MiB, fully written by k2)

#define OUT_F4 (BB * LL * DD / 4)  // 4,194,304 float4s in out
#define CHUNKS_Q 64                // blocks per batch in k_reduce_q
#define ROWS_Q (LL / CHUNKS_Q)     // 512 rows per block

// ---------------- Kernel 1: per-chunk partials of sum_l relu(q)+eps ----------------
// 512 blocks x 256 threads. Also zero-fills the FIRST half of out.
__global__ __launch_bounds__(256) void k_reduce_q(const float* __restrict__ q,
                                                  double* __restrict__ part,
                                                  float* __restrict__ out) {
    // zero-fill: 2,097,152 f4 / 512 blocks = 4096 per block = 16 per thread
    {
        f4 z = (f4)(0.0f);
        f4* oz = (f4*)out + (size_t)blockIdx.x * 4096 + threadIdx.x;
#pragma unroll
        for (int i = 0; i < 16; ++i) oz[i * 256] = z;
    }

    int b     = blockIdx.x >> 6;           // /CHUNKS_Q
    int chunk = blockIdx.x & (CHUNKS_Q - 1);
    int quad  = threadIdx.x & 15;          // which float4 of the 64-wide row
    int rowg  = threadIdx.x >> 4;          // 16 row-groups

    const f4* qb = (const f4*)(q + (size_t)b * LL * DD);
    const f4* base = qb + (size_t)(chunk * ROWS_Q + rowg) * 16 + quad;

    double a0 = 0.0, a1 = 0.0, a2 = 0.0, a3 = 0.0;
    f4 vb[8];
#pragma unroll
    for (int batch = 0; batch < 4; ++batch) {
#pragma unroll
        for (int j = 0; j < 8; ++j)
            vb[j] = base[(size_t)(batch * 8 + j) * 256];   // 16 rows = 256 f4 stride
#pragma unroll
        for (int j = 0; j < 8; ++j) {
            a0 += (double)fmaxf(vb[j].x, 0.0f) + 1e-3;
            a1 += (double)fmaxf(vb[j].y, 0.0f) + 1e-3;
            a2 += (double)fmaxf(vb[j].z, 0.0f) + 1e-3;
            a3 += (double)fmaxf(vb[j].w, 0.0f) + 1e-3;
        }
    }

    __shared__ double lds[16][16][5];   // [5] pads away bank conflicts
    lds[rowg][quad][0] = a0; lds[rowg][quad][1] = a1;
    lds[rowg][quad][2] = a2; lds[rowg][quad][3] = a3;
    __syncthreads();
    for (int s = 8; s > 0; s >>= 1) {
        if (rowg < s) {
            lds[rowg][quad][0] += lds[rowg + s][quad][0];
            lds[rowg][quad][1] += lds[rowg + s][quad][1];
            lds[rowg][quad][2] += lds[rowg + s][quad][2];
            lds[rowg][quad][3] += lds[rowg + s][quad][3];
        }
        __syncthreads();
    }
    if (rowg == 0) {
        double* pp = part + ((size_t)b * CHUNKS_Q + chunk) * DD;
        pp[quad * 4 + 0] = lds[0][quad][0];
        pp[quad * 4 + 1] = lds[0][quad][1];
        pp[quad * 4 + 2] = lds[0][quad][2];
        pp[quad * 4 + 3] = lds[0][quad][3];
    }
}

// ---------------- Kernel 2: reduce partials -> rq, then scores ----------------
// 1024 blocks x 256 threads, 256 rows each. Also zero-fills the SECOND half of out.
__global__ __launch_bounds__(256) void k_scores(const float* __restrict__ k,
                                                const double* __restrict__ part,
                                                double* __restrict__ scores,
                                                float* __restrict__ out) {
    __shared__ double s_part[4][DD];
    __shared__ double s_rq[DD];

    {
        f4 z = (f4)(0.0f);
        f4* oz = (f4*)out + (size_t)(OUT_F4 / 2)
               + (size_t)blockIdx.x * 2048 + threadIdx.x;
#pragma unroll
        for (int i = 0; i < 8; ++i) oz[i * 256] = z;
    }

    const int RPB = 256;
    int b     = blockIdx.x >> 7;          // /(LL/RPB)
    int chunk = blockIdx.x & 127;

    // ---- reconstruct rq[b,:] from the 64 chunk-partials (L2-hot, coalesced) ----
    {
        int d = threadIdx.x & 63;
        int g = threadIdx.x >> 6;   // 0..3
        const double* pp = part + (size_t)b * CHUNKS_Q * DD;
        double acc = 0.0;
#pragma unroll
        for (int j = 0; j < 16; ++j)
            acc += pp[(size_t)(g * 16 + j) * DD + d];
        s_part[g][d] = acc;
    }
    __syncthreads();
    if (threadIdx.x < DD) {
        int d = threadIdx.x;
        s_rq[d] = (s_part[0][d] + s_part[1][d]) + (s_part[2][d] + s_part[3][d]);
    }
    __syncthreads();

    int sub   = threadIdx.x & 15;
    int rowIn = threadIdx.x >> 4;

    double r0 = s_rq[sub * 4 + 0];
    double r1 = s_rq[sub * 4 + 1];
    double r2 = s_rq[sub * 4 + 2];
    double r3 = s_rq[sub * 4 + 3];

    const f4* kb = (const f4*)(k + (size_t)b * LL * DD);
    int l0 = chunk * RPB;
    const f4* base = kb + (size_t)(l0 + rowIn) * 16 + sub;

    f4 vb[8];
    double sv[8];
#pragma unroll
    for (int batch = 0; batch < 2; ++batch) {
#pragma unroll
        for (int i = 0; i < 8; ++i)
            vb[i] = base[(size_t)(batch * 8 + i) * 256];
#pragma unroll
        for (int i = 0; i < 8; ++i) {
            sv[i] = r0 * ((double)fmaxf(vb[i].x, 0.0f) + 1e-3)
                  + r1 * ((double)fmaxf(vb[i].y, 0.0f) + 1e-3)
                  + r2 * ((double)fmaxf(vb[i].z, 0.0f) + 1e-3)
                  + r3 * ((double)fmaxf(vb[i].w, 0.0f) + 1e-3);
        }
#pragma unroll
        for (int i = 0; i < 8; ++i) {
            double s = sv[i];
            s += __shfl_xor(s, 1, 16);
            s += __shfl_xor(s, 2, 16);
            s += __shfl_xor(s, 4, 16);
            s += __shfl_xor(s, 8, 16);
            if (sub == 0)
                scores[(size_t)b * LL + l0 + rowIn + 16 * (batch * 8 + i)] = s;
        }
    }
}

// ---------------- Kernel 3: radix select + gather selected V rows ----------------
// One block per batch, 1024 threads, 32 keys/thread (16x 16B vector loads).
// Positive doubles -> uint64 bit pattern preserves ordering.
// Early exit: once the chosen radix bucket holds exactly 1 key, that key IS the cutoff.
#define NCOPY 16
#define HSTRIDE 257
#define MAXSEL 96
__global__ __launch_bounds__(1024) void k_select_gather(const double* __restrict__ scores,
                                                        const int* __restrict__ topk_p,
                                                        const float* __restrict__ v,
                                                        float* __restrict__ out) {
    const int T = 1024;
    const int KPT = LL / T;  // 32
    int b   = blockIdx.x;
    int tid = threadIdx.x;

    const u64x2* sb2 = (const u64x2*)(scores + (size_t)b * LL);

    unsigned long long key[KPT];
    unsigned long long myAnd = ~0ULL, myOr = 0ULL;
#pragma unroll
    for (int j = 0; j < KPT / 2; ++j) {
        u64x2 p = sb2[tid + j * T];
        key[2 * j]     = p.x;
        key[2 * j + 1] = p.y;
        myAnd &= p.x & p.y;
        myOr  |= p.x | p.y;
    }

    __shared__ unsigned long long sAnd[16], sOr[16];
#pragma unroll
    for (int off = 32; off >= 1; off >>= 1) {
        myAnd &= __shfl_down(myAnd, off);
        myOr  |= __shfl_down(myOr, off);
    }
    int wave = tid >> 6;
    if ((tid & 63) == 0) { sAnd[wave] = myAnd; sOr[wave] = myOr; }
    __syncthreads();
    __shared__ unsigned long long bAnd, bOr;
    if (tid == 0) {
        unsigned long long a = ~0ULL, o = 0ULL;
#pragma unroll
        for (int w = 0; w < 16; ++w) { a &= sAnd[w]; o |= sOr[w]; }
        bAnd = a; bOr = o;
    }

    __shared__ unsigned int hist[NCOPY * HSTRIDE];
    __shared__ unsigned int sTot[256];
    __shared__ unsigned long long sh_prefix;
    __shared__ int sh_r;
    __shared__ int sh_digit, sh_newr, sh_cnt, sh_done;
    if (tid == 0) { sh_prefix = 0ULL; sh_r = topk_p[0]; sh_done = 0; }
    __syncthreads();

    int copy = tid & (NCOPY - 1);

    for (int shift = 56; shift >= 0; shift -= 8) {
        if (sh_done) break;

        unsigned int dA = (unsigned int)(bAnd >> shift) & 255u;
        unsigned int dO = (unsigned int)(bOr  >> shift) & 255u;
        if (dA == dO) {
            if (tid == 0) sh_prefix |= ((unsigned long long)dA << shift);
            __syncthreads();
            continue;
        }

        for (int i = tid; i < NCOPY * HSTRIDE; i += T) hist[i] = 0;
        __syncthreads();

        unsigned long long prefix = sh_prefix;
        unsigned long long hm = (shift == 56) ? 0ULL : (~0ULL << (shift + 8));
        int r = sh_r;

#pragma unroll
        for (int i = 0; i < KPT; ++i) {
            unsigned long long kk = key[i];
            if ((kk & hm) == prefix) {
                unsigned int d = (unsigned int)(kk >> shift) & 255u;
                atomicAdd(&hist[copy * HSTRIDE + d], 1u);
            }
        }
        __syncthreads();

        if (tid < 256) {
            unsigned int t = 0;
#pragma unroll
            for (int c = 0; c < NCOPY; ++c) t += hist[c * HSTRIDE + tid];
            sTot[tid] = t;
        }
        __syncthreads();

        for (int s = 1; s < 256; s <<= 1) {
            unsigned int vv = 0;
            if (tid < 256 && tid + s < 256) vv = sTot[tid + s];
            __syncthreads();
            if (tid < 256) sTot[tid] += vv;
            __syncthreads();
        }

        if (tid < 256) {
            unsigned int suf  = sTot[tid];
            unsigned int sufn = (tid == 255) ? 0u : sTot[tid + 1];
            if (suf > (unsigned int)r && sufn <= (unsigned int)r) {
                sh_digit = tid;
                sh_newr  = r - (int)sufn;
                sh_cnt   = (int)(suf - sufn);
            }
        }
        __syncthreads();
        if (tid == 0) {
            sh_prefix |= ((unsigned long long)sh_digit << shift);
            sh_r = sh_newr;
        }
        __syncthreads();

        if (sh_cnt == 1 && shift > 0) {
            unsigned long long pfx = sh_prefix;
            unsigned long long hm2 = ~0ULL << shift;
#pragma unroll
            for (int i = 0; i < KPT; ++i) {
                if ((key[i] & hm2) == pfx) {
                    sh_prefix = key[i];   // unique owner
                    sh_done = 1;
                }
            }
        }
        __syncthreads();
    }

    // ---- gather phase: rows with key > cutoff get V copied into out ----
    __shared__ int s_cnt;
    __shared__ int s_idx[MAXSEL];
    if (tid == 0) s_cnt = 0;
    __syncthreads();
    unsigned long long cb = sh_prefix;
#pragma unroll
    for (int i = 0; i < KPT; ++i) {
        if (key[i] > cb) {
            int slot = atomicAdd(&s_cnt, 1);
            if (slot < MAXSEL)
                s_idx[slot] = 2 * (tid + (i >> 1) * T) + (i & 1);
        }
    }
    __syncthreads();
    int cnt = s_cnt < MAXSEL ? s_cnt : MAXSEL;

    int g      = tid >> 4;   // 64 groups of 16 lanes
    int lane16 = tid & 15;
    for (int r = g; r < cnt; r += 64) {
        size_t rowOff = ((size_t)b * LL + s_idx[r]) * DD;
        const f4* vrow = (const f4*)(v + rowOff);
        f4*       orow = (f4*)(out + rowOff);
        orow[lane16] = vrow[lane16];
    }
}

extern "C" void kernel_launch(void* const* d_in, const int* in_sizes, int n_in,
                              void* d_out, int out_size, void* d_ws, size_t ws_size,
                              hipStream_t stream) {
    const float* q = (const float*)d_in[0];
    const float* k = (const float*)d_in[1];
    const float* v = (const float*)d_in[2];
    const int* topk = (const int*)d_in[3];
    float* out = (float*)d_out;

    double* part   = (double*)d_ws;                        // 256 KB, fully written by k1
    double* scores = (double*)((char*)d_ws + 262144);      // 2 MiB, fully written by k2

    k_reduce_q<<<BB * CHUNKS_Q, 256, 0, stream>>>(q, part, out);
    k_scores<<<BB * (LL / 256), 256, 0, stream>>>(k, part, scores, out);
    k_select_gather<<<BB, 1024, 0, stream>>>(scores, topk, v, out);
}